// Round 11
// baseline (19.542 us; speedup 1.0000x reference)
//
#include <hip/hip_runtime.h>
#include <stdint.h>
#include <math.h>

#define NUM_TOKENS 16384
#define NUM_EXPERTS 64
#define TOP_K 8

__device__ __forceinline__ uint32_t rotl32(uint32_t v, int s) {
  return (v << s) | (v >> (32 - s));
}

// Threefry-2x32, 20 rounds, key (0,42) -> JAX jax.random.key(42).
// Partitionable-mode 32-bit draw for flat index j: counter (0, j), return o0 ^ o1.
__device__ __forceinline__ uint32_t threefry_bits(uint32_t c0, uint32_t c1) {
  const uint32_t k0 = 0u, k1 = 42u;
  const uint32_t k2 = k0 ^ k1 ^ 0x1BD11BDAu;
  uint32_t x0 = c0 + k0, x1 = c1 + k1;
#define TF_R(r) { x0 += x1; x1 = rotl32(x1, (r)); x1 ^= x0; }
  TF_R(13) TF_R(15) TF_R(26) TF_R(6)  x0 += k1; x1 += k2 + 1u;
  TF_R(17) TF_R(29) TF_R(16) TF_R(24) x0 += k2; x1 += k0 + 2u;
  TF_R(13) TF_R(15) TF_R(26) TF_R(6)  x0 += k0; x1 += k1 + 3u;
  TF_R(17) TF_R(29) TF_R(16) TF_R(24) x0 += k1; x1 += k2 + 4u;
  TF_R(13) TF_R(15) TF_R(26) TF_R(6)  x0 += k2; x1 += k0 + 5u;
#undef TF_R
  return x0 ^ x1;
}

// Fast f64 reciprocal: v_rcp_f64 + 2 Newton steps -> ~1 ulp (vs the
// compiler's ~2x slower correctly-rounded div sequence). Feeds a series
// with 1e-13 rel budget, so CR of the final f32 is unaffected.
__device__ __forceinline__ double fast_rcp_f64(double d) {
  double r = __builtin_amdgcn_rcp(d);
  r = __builtin_fma(__builtin_fma(-d, r, 1.0), r, r);
  r = __builtin_fma(__builtin_fma(-d, r, 1.0), r, r);
  return r;
}

// Lean branch-free f64 exp for x in [-9, 9] (no overflow/denormal paths).
// Cody-Waite + degree-11 Taylor; rel err ~6e-15 -> f32-CR w.p. ~1-1e-7/call.
__device__ __forceinline__ double fast_exp_f64(double x) {
  const double LOG2E = 1.4426950408889634074;
  const double SHIFT = 6755399441055744.0;       // 1.5 * 2^52
  double kd = __builtin_fma(x, LOG2E, SHIFT);
  int ki = (int)(uint32_t)__double_as_longlong(kd);  // low bits = k (2's comp)
  kd -= SHIFT;                                    // k as double
  const double LN2_HI = 6.93147180369123816490e-01;
  const double LN2_LO = 1.90821492927058770002e-10;
  double r = __builtin_fma(-kd, LN2_HI, x);
  r = __builtin_fma(-kd, LN2_LO, r);
  double p = 1.0 / 39916800.0;                    // 1/11!
  p = __builtin_fma(p, r, 1.0 / 3628800.0);
  p = __builtin_fma(p, r, 1.0 / 362880.0);
  p = __builtin_fma(p, r, 1.0 / 40320.0);
  p = __builtin_fma(p, r, 1.0 / 5040.0);
  p = __builtin_fma(p, r, 1.0 / 720.0);
  p = __builtin_fma(p, r, 1.0 / 120.0);
  p = __builtin_fma(p, r, 1.0 / 24.0);
  p = __builtin_fma(p, r, 1.0 / 6.0);
  p = __builtin_fma(p, r, 0.5);
  p = __builtin_fma(p, r, 1.0);
  p = __builtin_fma(p, r, 1.0);
  double scale = __longlong_as_double((long long)(1023 + ki) << 52);
  return p * scale;
}

// Lean f32 log via f64 for t in (1e-7, 1.5], normal positive.
// sqrt(2)-centered mantissa + atanh series to z^17; rel err ~1e-15.
__device__ __forceinline__ float fast_logf_cr(float tf) {
  uint32_t b = __float_as_uint(tf);
  uint32_t madj = (b & 0x007FFFFFu) | 0x3F800000u;   // m in [1,2)
  int e = (int)(b >> 23) - 127;
  int up = (madj >= 0x3FB504F3u) ? 1 : 0;            // m >= sqrt(2) -> halve
  e += up;
  madj -= ((uint32_t)up << 23);                      // m in [0.7071, 1.4142)
  double m = (double)__uint_as_float(madj);
  double z = (m - 1.0) * fast_rcp_f64(m + 1.0);      // |z| <= 0.1716
  double z2 = z * z;
  double q = 2.0 / 17.0;
  q = __builtin_fma(q, z2, 2.0 / 15.0);
  q = __builtin_fma(q, z2, 2.0 / 13.0);
  q = __builtin_fma(q, z2, 2.0 / 11.0);
  q = __builtin_fma(q, z2, 2.0 / 9.0);
  q = __builtin_fma(q, z2, 2.0 / 7.0);
  q = __builtin_fma(q, z2, 2.0 / 5.0);
  q = __builtin_fma(q, z2, 2.0 / 3.0);
  q = __builtin_fma(q, z2, 2.0);
  double lnm = q * z;
  const double LN2 = 0.69314718055994530942;
  return (float)__builtin_fma((double)e, LN2, lnm);
}

// XLA CHLO erfinv f32 (Giles polynomial), with XLA EmitLog1p semantics.
// No FP contraction: XLA emits unfused fmul/fadd.
__device__ __forceinline__ float xla_erfinv_f32(float x) {
#pragma clang fp contract(off)
  float s = x * x;          // x*x, exact IEEE mul
  float nx = -s;            // -x*x
  float l1p;
  if (__builtin_fabsf(nx) < 1e-4f) {
    // EmitLog1p small branch: ((-0.5*x) + 1) * x
    l1p = ((-0.5f * nx) + 1.0f) * nx;
  } else {
    float t = nx + 1.0f;
    l1p = fast_logf_cr(t);    // f32-CR logf emulation (lean f64 path)
  }
  float w = -l1p;
  float p;
  if (w < 5.0f) {
    float h = w - 2.5f;
    p = 2.81022636e-08f;
    p = 3.43273939e-07f  + p * h;
    p = -3.5233877e-06f  + p * h;
    p = -4.39150654e-06f + p * h;
    p = 0.00021858087f   + p * h;
    p = -0.00125372503f  + p * h;
    p = -0.00417768164f  + p * h;
    p = 0.246640727f     + p * h;
    p = 1.50140941f      + p * h;
  } else {
    float h = __builtin_sqrtf(w) - 3.0f;
    p = -0.000200214257f;
    p = 0.000100950558f  + p * h;
    p = 0.00134934322f   + p * h;
    p = -0.00367342844f  + p * h;
    p = 0.00573950773f   + p * h;
    p = -0.0076224613f   + p * h;
    p = 0.00943887047f   + p * h;
    p = 1.00167406f      + p * h;
    p = 2.83297682f      + p * h;
  }
  return p * x;
}

// One wave (64 lanes) per token; lane = expert id. f32 chain semantics
// unchanged (bit-exact verified R2-R10). Rank via sortable u64 keys
// (K = ord(adj)<<6 | (63-lane); K_j > K_i == "j outranks i" incl. stable
// lower-index tie-break), all-pairs compare via LDS broadcast ulonglong2
// reads. R9 lesson: do NOT replace with v_readlane (serial VALU issue,
// +3.1 µs); LDS broadcasts ride the separate LDS pipe concurrent w/ VALU.
// NEW (R11): selection mask sidecar — __ballot(rank<TOP_K) is the token's
// entire histogram contribution (bit e = expert e selected); lane 0
// stores one u64/token so the hist kernel never re-reads the 1MB indices.
__global__ __launch_bounds__(256) void router_kernel(
    const float* __restrict__ bias, float* __restrict__ out,
    float* __restrict__ hist, unsigned long long* __restrict__ masks) {
#pragma clang fp contract(off)
  __shared__ unsigned long long keybuf[4][64];
  __shared__ float sel[4][TOP_K];
  const int wv   = threadIdx.x >> 6;
  const int lane = threadIdx.x & 63;
  const int t    = blockIdx.x * 4 + wv;

  // zero the hist region (no memset graph node); only block 0 touches it,
  // and hist_kernel runs in the next dispatch.
  if (blockIdx.x == 0 && threadIdx.x < NUM_EXPERTS) hist[threadIdx.x] = 0.0f;

  const uint32_t j = (uint32_t)t * 64u + (uint32_t)lane;

  // --- rnd = jax.random.normal(key(42)) element j ---
  uint32_t bits = threefry_bits(0u, j);
  float f = __uint_as_float((bits >> 9) | 0x3F800000u) - 1.0f;  // [0,1), exact
  const float LO = __uint_as_float(0xBF7FFFFFu);                // nextafter(-1,0)
  float u = (f * 2.0f) + LO;   // f*2 exact; maxval-minval rounds to 2.0f
  u = fmaxf(LO, u);
  float er = xla_erfinv_f32(u);
  float n = __uint_as_float(0x3FB504F3u) * er;                  // f32(sqrt(2)) * erfinv

  // --- sigmoid via XLA LogisticExpander: 1/(1+exp(-x)) ---
  float efl = (float)fast_exp_f64(-(double)n);                  // CR expf emulation
  float score = 1.0f / (1.0f + efl);                            // HIP f32 div is CR
  float adj = score + bias[lane];                               // selection key

  // --- sortable key: total order == (value desc, index asc) ---
  uint32_t ab = __float_as_uint(adj);
  uint32_t ord = ab ^ ((uint32_t)((int32_t)ab >> 31) | 0x80000000u);
  unsigned long long key =
      ((unsigned long long)ord << 6) | (unsigned long long)(63 - lane);

  keybuf[wv][lane] = key;
  asm volatile("s_waitcnt lgkmcnt(0)" ::: "memory");  // wave-local visibility

  int rank = 0;
  const ulonglong2* kb = (const ulonglong2*)(&keybuf[wv][0]);
#pragma unroll
  for (int i = 0; i < 32; ++i) {
    ulonglong2 kv = kb[i];   // same address across lanes -> LDS broadcast
    rank += (kv.x > key) ? 1 : 0;
    rank += (kv.y > key) ? 1 : 0;
  }

  const bool win = (rank < TOP_K);
  unsigned long long selmask = __ballot(win);  // bit e = expert e selected
  if (lane == 0 && masks) masks[t] = selmask;

  if (win) sel[wv][rank] = score;
  asm volatile("s_waitcnt lgkmcnt(0)" ::: "memory");  // wave-local visibility

  // sequential sum over the 8 selected scores (rank order preserved
  // exactly: x,y,z,w of each float4 in order), like jnp.sum
  const float4* sv = (const float4*)(&sel[wv][0]);
  float4 s0 = sv[0];            // broadcast LDS reads (same addr all lanes)
  float4 s1 = sv[1];
  float sum = s0.x + s0.y;
  sum = sum + s0.z; sum = sum + s0.w;
  sum = sum + s1.x; sum = sum + s1.y;
  sum = sum + s1.z; sum = sum + s1.w;
  float denom = sum + 1e-20f;

  if (win) {
    float v = (score / denom) * 2.5f;
    out[t * TOP_K + rank] = v;                                   // top_scores
    out[NUM_TOKENS * TOP_K + t * TOP_K + rank] = (float)lane;    // indices (as f32)
  }
}

// Bit-column histogram from selection masks: lane owns expert=lane.
// 16 blocks x 1024 threads (16 waves); wave wv handles chunk
// blockIdx*16+wv of 64 masks. All 64 lanes read the SAME mask word
// (wave-uniform -> single fetch), extract their bit, accumulate.
// Zero LDS atomics, 128 KB total read, 16 atomic txns/cacheline merge.
__global__ __launch_bounds__(1024) void hist_mask_kernel(
    const unsigned long long* __restrict__ masks, float* __restrict__ hist) {
  __shared__ unsigned int partial[16][NUM_EXPERTS];
  const int wv   = threadIdx.x >> 6;
  const int lane = threadIdx.x & 63;
  const int base = (blockIdx.x * 16 + wv) * 64;   // 256 chunks of 64 tokens

  unsigned int cnt = 0;
#pragma unroll
  for (int i = 0; i < 64; ++i) {
    unsigned long long w = masks[base + i];       // wave-uniform broadcast
    cnt += (unsigned int)((w >> lane) & 1ull);
  }
  partial[wv][lane] = cnt;
  __syncthreads();

  if (wv == 0) {
    unsigned int total = 0;
#pragma unroll
    for (int k = 0; k < 16; ++k) total += partial[k][lane];  // 2-way bank = free
    atomicAdd(&hist[lane], (float)total);  // exact: integer sums < 2^24
  }
}

// Fallback hist (verified R10 path) if d_ws is too small for the masks.
#define HIST_BLOCKS 32
__global__ __launch_bounds__(256) void hist_kernel(
    const float* __restrict__ idx, float* __restrict__ hist) {
  __shared__ unsigned int h[NUM_EXPERTS];
  if (threadIdx.x < NUM_EXPERTS) h[threadIdx.x] = 0u;
  __syncthreads();
  const int n4 = (NUM_TOKENS * TOP_K) / 4;          // 32768 float4s
  const float4* idx4 = (const float4*)idx;
  for (int i = blockIdx.x * 256 + threadIdx.x; i < n4; i += HIST_BLOCKS * 256) {
    float4 v = idx4[i];
    atomicAdd(&h[(int)v.x], 1u);
    atomicAdd(&h[(int)v.y], 1u);
    atomicAdd(&h[(int)v.z], 1u);
    atomicAdd(&h[(int)v.w], 1u);
  }
  __syncthreads();
  if (threadIdx.x < NUM_EXPERTS) {
    unsigned int c = h[threadIdx.x];
    if (c) atomicAdd(&hist[threadIdx.x], (float)c);  // exact: integer sums < 2^24
  }
}

extern "C" void kernel_launch(void* const* d_in, const int* in_sizes, int n_in,
                              void* d_out, int out_size, void* d_ws, size_t ws_size,
                              hipStream_t stream) {
  (void)in_sizes; (void)n_in; (void)out_size;
  // Forward output is independent of x (d_in[0]) and gate_w (d_in[1]):
  // RandomSTE replaces logits with fresh normals in the forward pass.
  const float* bias = (const float*)d_in[2];
  float* out = (float*)d_out;
  float* idx_region = out + NUM_TOKENS * TOP_K;
  float* hist = out + 2 * NUM_TOKENS * TOP_K;

  const bool use_masks =
      (d_ws != nullptr) && (ws_size >= NUM_TOKENS * sizeof(unsigned long long));
  unsigned long long* masks =
      use_masks ? (unsigned long long*)d_ws : nullptr;

  router_kernel<<<NUM_TOKENS / 4, 256, 0, stream>>>(bias, out, hist, masks);
  if (use_masks) {
    hist_mask_kernel<<<16, 1024, 0, stream>>>(masks, hist);
  } else {
    hist_kernel<<<HIST_BLOCKS, 256, 0, stream>>>(idx_region, hist);
  }
}

// Round 12
// 17.393 us; speedup vs baseline: 1.1236x; 1.1236x over previous
//
#include <hip/hip_runtime.h>
#include <stdint.h>
#include <math.h>

#define NUM_TOKENS 16384
#define NUM_EXPERTS 64
#define TOP_K 8

__device__ __forceinline__ uint32_t rotl32(uint32_t v, int s) {
  return (v << s) | (v >> (32 - s));
}

// Threefry-2x32, 20 rounds, key (0,42) -> JAX jax.random.key(42).
// Partitionable-mode 32-bit draw for flat index j: counter (0, j), return o0 ^ o1.
__device__ __forceinline__ uint32_t threefry_bits(uint32_t c0, uint32_t c1) {
  const uint32_t k0 = 0u, k1 = 42u;
  const uint32_t k2 = k0 ^ k1 ^ 0x1BD11BDAu;
  uint32_t x0 = c0 + k0, x1 = c1 + k1;
#define TF_R(r) { x0 += x1; x1 = rotl32(x1, (r)); x1 ^= x0; }
  TF_R(13) TF_R(15) TF_R(26) TF_R(6)  x0 += k1; x1 += k2 + 1u;
  TF_R(17) TF_R(29) TF_R(16) TF_R(24) x0 += k2; x1 += k0 + 2u;
  TF_R(13) TF_R(15) TF_R(26) TF_R(6)  x0 += k0; x1 += k1 + 3u;
  TF_R(17) TF_R(29) TF_R(16) TF_R(24) x0 += k1; x1 += k2 + 4u;
  TF_R(13) TF_R(15) TF_R(26) TF_R(6)  x0 += k2; x1 += k0 + 5u;
#undef TF_R
  return x0 ^ x1;
}

// Fast f64 reciprocal: v_rcp_f64 + 2 Newton steps -> ~1 ulp. Feeds a series
// with 1e-12 rel budget, so CR of the final f32 is unaffected.
__device__ __forceinline__ double fast_rcp_f64(double d) {
  double r = __builtin_amdgcn_rcp(d);
  r = __builtin_fma(__builtin_fma(-d, r, 1.0), r, r);
  r = __builtin_fma(__builtin_fma(-d, r, 1.0), r, r);
  return r;
}

// Lean branch-free f64 exp for |x| <= 9 (no overflow/denormal paths).
// Cody-Waite + degree-9 Taylor; |r|<=0.347 -> tail r^10/10! ~ 7e-12 rel,
// far below the ~6e-8 band where the rounded f32 could flip (R12 trim).
__device__ __forceinline__ double fast_exp_f64(double x) {
  const double LOG2E = 1.4426950408889634074;
  const double SHIFT = 6755399441055744.0;       // 1.5 * 2^52
  double kd = __builtin_fma(x, LOG2E, SHIFT);
  int ki = (int)(uint32_t)__double_as_longlong(kd);  // low bits = k (2's comp)
  kd -= SHIFT;                                    // k as double
  const double LN2_HI = 6.93147180369123816490e-01;
  const double LN2_LO = 1.90821492927058770002e-10;
  double r = __builtin_fma(-kd, LN2_HI, x);
  r = __builtin_fma(-kd, LN2_LO, r);
  double p = 1.0 / 362880.0;                      // 1/9!
  p = __builtin_fma(p, r, 1.0 / 40320.0);
  p = __builtin_fma(p, r, 1.0 / 5040.0);
  p = __builtin_fma(p, r, 1.0 / 720.0);
  p = __builtin_fma(p, r, 1.0 / 120.0);
  p = __builtin_fma(p, r, 1.0 / 24.0);
  p = __builtin_fma(p, r, 1.0 / 6.0);
  p = __builtin_fma(p, r, 0.5);
  p = __builtin_fma(p, r, 1.0);
  p = __builtin_fma(p, r, 1.0);
  double scale = __longlong_as_double((long long)(1023 + ki) << 52);
  return p * scale;
}

// Lean f32 log via f64 for t in (1e-7, 1.5], normal positive.
// sqrt(2)-centered mantissa + atanh series to z^13; |z|<=0.1716 ->
// tail 2z^15/15 ~ 4.5e-13 abs (rel ~z^14 when lnm small) (R12 trim).
__device__ __forceinline__ float fast_logf_cr(float tf) {
  uint32_t b = __float_as_uint(tf);
  uint32_t madj = (b & 0x007FFFFFu) | 0x3F800000u;   // m in [1,2)
  int e = (int)(b >> 23) - 127;
  int up = (madj >= 0x3FB504F3u) ? 1 : 0;            // m >= sqrt(2) -> halve
  e += up;
  madj -= ((uint32_t)up << 23);                      // m in [0.7071, 1.4142)
  double m = (double)__uint_as_float(madj);
  double z = (m - 1.0) * fast_rcp_f64(m + 1.0);      // |z| <= 0.1716
  double z2 = z * z;
  double q = 2.0 / 13.0;
  q = __builtin_fma(q, z2, 2.0 / 11.0);
  q = __builtin_fma(q, z2, 2.0 / 9.0);
  q = __builtin_fma(q, z2, 2.0 / 7.0);
  q = __builtin_fma(q, z2, 2.0 / 5.0);
  q = __builtin_fma(q, z2, 2.0 / 3.0);
  q = __builtin_fma(q, z2, 2.0);
  double lnm = q * z;
  const double LN2 = 0.69314718055994530942;
  return (float)__builtin_fma((double)e, LN2, lnm);
}

// XLA CHLO erfinv f32 (Giles polynomial), with XLA EmitLog1p semantics.
// No FP contraction: XLA emits unfused fmul/fadd.
__device__ __forceinline__ float xla_erfinv_f32(float x) {
#pragma clang fp contract(off)
  float s = x * x;          // x*x, exact IEEE mul
  float nx = -s;            // -x*x
  float l1p;
  if (__builtin_fabsf(nx) < 1e-4f) {
    // EmitLog1p small branch: ((-0.5*x) + 1) * x
    l1p = ((-0.5f * nx) + 1.0f) * nx;
  } else {
    float t = nx + 1.0f;
    l1p = fast_logf_cr(t);    // f32-CR logf emulation (lean f64 path)
  }
  float w = -l1p;
  float p;
  if (w < 5.0f) {
    float h = w - 2.5f;
    p = 2.81022636e-08f;
    p = 3.43273939e-07f  + p * h;
    p = -3.5233877e-06f  + p * h;
    p = -4.39150654e-06f + p * h;
    p = 0.00021858087f   + p * h;
    p = -0.00125372503f  + p * h;
    p = -0.00417768164f  + p * h;
    p = 0.246640727f     + p * h;
    p = 1.50140941f      + p * h;
  } else {
    float h = __builtin_sqrtf(w) - 3.0f;
    p = -0.000200214257f;
    p = 0.000100950558f  + p * h;
    p = 0.00134934322f   + p * h;
    p = -0.00367342844f  + p * h;
    p = 0.00573950773f   + p * h;
    p = -0.0076224613f   + p * h;
    p = 0.00943887047f   + p * h;
    p = 1.00167406f      + p * h;
    p = 2.83297682f      + p * h;
  }
  return p * x;
}

// One wave (64 lanes) per token; lane = expert id. f32 chain semantics
// unchanged (bit-exact verified R2-R11). Rank via sortable u64 keys
// (K = ord(adj)<<6 | (63-lane); K_j > K_i == "j outranks i" incl. stable
// lower-index tie-break), all-pairs compare via LDS broadcast ulonglong2
// reads. R9 lesson: NOT v_readlane (serial VALU issue, +3.1 µs).
// R11 lesson: no mask sidecar (scattered 8B stores + 1-wave/CU hist, +2 µs).
__global__ __launch_bounds__(256) void router_kernel(
    const float* __restrict__ bias, float* __restrict__ out,
    float* __restrict__ hist) {
#pragma clang fp contract(off)
  __shared__ unsigned long long keybuf[4][64];
  __shared__ float sel[4][TOP_K];
  const int wv   = threadIdx.x >> 6;
  const int lane = threadIdx.x & 63;
  const int t    = blockIdx.x * 4 + wv;

  // zero the hist region (no memset graph node); only block 0 touches it,
  // and hist_kernel runs in the next dispatch.
  if (blockIdx.x == 0 && threadIdx.x < NUM_EXPERTS) hist[threadIdx.x] = 0.0f;

  const uint32_t j = (uint32_t)t * 64u + (uint32_t)lane;

  // --- rnd = jax.random.normal(key(42)) element j ---
  uint32_t bits = threefry_bits(0u, j);
  float f = __uint_as_float((bits >> 9) | 0x3F800000u) - 1.0f;  // [0,1), exact
  const float LO = __uint_as_float(0xBF7FFFFFu);                // nextafter(-1,0)
  float u = (f * 2.0f) + LO;   // f*2 exact; maxval-minval rounds to 2.0f
  u = fmaxf(LO, u);
  float er = xla_erfinv_f32(u);
  float n = __uint_as_float(0x3FB504F3u) * er;                  // f32(sqrt(2)) * erfinv

  // --- sigmoid via XLA LogisticExpander: 1/(1+exp(-x)) ---
  float efl = (float)fast_exp_f64(-(double)n);                  // CR expf emulation
  float score = 1.0f / (1.0f + efl);                            // HIP f32 div is CR
  float adj = score + bias[lane];                               // selection key

  // --- sortable key: total order == (value desc, index asc) ---
  uint32_t ab = __float_as_uint(adj);
  uint32_t ord = ab ^ ((uint32_t)((int32_t)ab >> 31) | 0x80000000u);
  unsigned long long key =
      ((unsigned long long)ord << 6) | (unsigned long long)(63 - lane);

  keybuf[wv][lane] = key;
  asm volatile("s_waitcnt lgkmcnt(0)" ::: "memory");  // wave-local visibility

  int rank = 0;
  const ulonglong2* kb = (const ulonglong2*)(&keybuf[wv][0]);
#pragma unroll
  for (int i = 0; i < 32; ++i) {
    ulonglong2 kv = kb[i];   // same address across lanes -> LDS broadcast
    rank += (kv.x > key) ? 1 : 0;
    rank += (kv.y > key) ? 1 : 0;
  }

  if (rank < TOP_K) sel[wv][rank] = score;
  asm volatile("s_waitcnt lgkmcnt(0)" ::: "memory");  // wave-local visibility

  // sequential sum over the 8 selected scores (rank order preserved
  // exactly: x,y,z,w of each float4 in order), like jnp.sum
  const float4* sv = (const float4*)(&sel[wv][0]);
  float4 s0 = sv[0];            // broadcast LDS reads (same addr all lanes)
  float4 s1 = sv[1];
  float sum = s0.x + s0.y;
  sum = sum + s0.z; sum = sum + s0.w;
  sum = sum + s1.x; sum = sum + s1.y;
  sum = sum + s1.z; sum = sum + s1.w;
  float denom = sum + 1e-20f;

  if (rank < TOP_K) {
    float v = (score / denom) * 2.5f;
    out[t * TOP_K + rank] = v;                                   // top_scores
    out[NUM_TOKENS * TOP_K + t * TOP_K + rank] = (float)lane;    // indices (as f32)
  }
}

// Parallel histogram: 32 blocks (32 atomic txns/cacheline at the merge —
// R5 model: ~10 ns per serialized line-txn; NEVER per-token atomics on
// 4 cachelines), per-block LDS partials, wave-coalesced global merges.
#define HIST_BLOCKS 32
__global__ __launch_bounds__(256) void hist_kernel(
    const float* __restrict__ idx, float* __restrict__ hist) {
  __shared__ unsigned int h[NUM_EXPERTS];
  if (threadIdx.x < NUM_EXPERTS) h[threadIdx.x] = 0u;
  __syncthreads();
  const int n4 = (NUM_TOKENS * TOP_K) / 4;          // 32768 float4s
  const float4* idx4 = (const float4*)idx;
  for (int i = blockIdx.x * 256 + threadIdx.x; i < n4; i += HIST_BLOCKS * 256) {
    float4 v = idx4[i];
    atomicAdd(&h[(int)v.x], 1u);
    atomicAdd(&h[(int)v.y], 1u);
    atomicAdd(&h[(int)v.z], 1u);
    atomicAdd(&h[(int)v.w], 1u);
  }
  __syncthreads();
  if (threadIdx.x < NUM_EXPERTS) {
    unsigned int c = h[threadIdx.x];
    if (c) atomicAdd(&hist[threadIdx.x], (float)c);  // exact: integer sums < 2^24
  }
}

extern "C" void kernel_launch(void* const* d_in, const int* in_sizes, int n_in,
                              void* d_out, int out_size, void* d_ws, size_t ws_size,
                              hipStream_t stream) {
  (void)in_sizes; (void)n_in; (void)d_ws; (void)ws_size; (void)out_size;
  // Forward output is independent of x (d_in[0]) and gate_w (d_in[1]):
  // RandomSTE replaces logits with fresh normals in the forward pass.
  const float* bias = (const float*)d_in[2];
  float* out = (float*)d_out;
  float* idx_region = out + NUM_TOKENS * TOP_K;
  float* hist = out + 2 * NUM_TOKENS * TOP_K;

  router_kernel<<<NUM_TOKENS / 4, 256, 0, stream>>>(bias, out, hist);
  hist_kernel<<<HIST_BLOCKS, 256, 0, stream>>>(idx_region, hist);
}